// Round 1
// baseline (239.562 us; speedup 1.0000x reference)
//
#include <hip/hip_runtime.h>
#include <hip/hip_bf16.h>
#include <math.h>

#define NH   4
#define DH   16
#define CH   64
#define KNN  10
#define KS   4
#define NV   4096
#define NB   4
#define MHID 256
#define BN   (NB * NV)

// canonical param-buffer offsets (f32 elements)
#define P_LN1G  0
#define P_LN1B  64
#define P_LN2G  128
#define P_LN2B  192
#define P_WQKV  256
#define P_BQKV  12544
#define P_WPROJ 12736
#define P_BPROJ 16832
#define P_W1    16896
#define P_B1    33280
#define P_W2    33536
#define P_B2    49920
#define P_TOT   49984

#define N_ING  (BN * CH + NB * NV * 3 + P_TOT + BN)   // 1,164,096
#define N_PACK (16384 + 16384 + 12288)                // 45,056

typedef __hip_bfloat16 bf16;
typedef __attribute__((ext_vector_type(8))) short short8;
typedef __attribute__((ext_vector_type(4))) float float4a;

__device__ __forceinline__ float b2f(bf16 x) { return __bfloat162float(x); }

__device__ __forceinline__ float cvt(const void* p, int i, int isbf) {
  return isbf ? b2f(((const bf16*)p)[i]) : ((const float*)p)[i];
}

__device__ __forceinline__ float wave_sum_f32(float v) {
#pragma unroll
  for (int m = 32; m >= 1; m >>= 1) v += __shfl_xor(v, m, 64);
  return v;
}

__device__ __forceinline__ float tanh_fast(float u) {
  float e = __expf(2.0f * u);
  return 1.0f - 2.0f / (e + 1.0f);
}

// identical d2 expression everywhere (exactness anchor)
__device__ __forceinline__ float d2f(float x, float y, float z,
                                     float qx, float qy, float qz) {
  float dx = x - qx, dy = y - qy, dz = z - qz;
  return dx * dx + dy * dy + dz * dz;
}

// branchless register top-K insert on (d2bits<<32)|idx keys.
// fully unrolled => all arr indices compile-time constant (stays in VGPRs).
__device__ __forceinline__ void knn_insert(unsigned long long* arr,
                                           unsigned long long key) {
  if (key < arr[KNN - 1]) {
#pragma unroll
    for (int t = 0; t < KNN; ++t) {
      unsigned long long a = arr[t];
      bool lt = key < a;
      unsigned long long mn = lt ? key : a;
      unsigned long long mx = lt ? a : key;
      arr[t] = mn;
      key = mx;
    }
  }
}

// ---------------- K0: fused detect + ingest + pack ----------------
__global__ __launch_bounds__(256) void k_prep(
    const void* xin, const void* coords, const void* maskr,
    const void* ln1g, const void* ln1b, const void* ln2g, const void* ln2b,
    const void* wqkv, const void* bqkv, const void* wproj, const void* bproj,
    const void* w1, const void* b1, const void* w2, const void* b2,
    float* __restrict__ xcan, float* __restrict__ ccan,
    float* __restrict__ pcan, int* __restrict__ mcan,
    unsigned short* __restrict__ w1p, unsigned short* __restrict__ w2p,
    unsigned short* __restrict__ wqp, int* __restrict__ flags)
{
  __shared__ int sfl[2];
  const int tid = threadIdx.x;
  if (tid < 64) {
    const unsigned short* xu = (const unsigned short*)xin;
    const unsigned* mu = (const unsigned*)maskr;
    int cnt = 0;
#pragma unroll
    for (int k = 0; k < 4; ++k) {
      unsigned short w = xu[tid * 4 + k];
      int e = (w >> 7) & 0xFF;
      cnt += (e >= 100 && e <= 140);
    }
#pragma unroll
    for (int m = 32; m >= 1; m >>= 1) cnt += __shfl_xor(cnt, m, 64);
    unsigned big = (mu[tid] > 1u) ? 1u : 0u;
#pragma unroll
    for (int m = 32; m >= 1; m >>= 1) big |= __shfl_xor(big, m, 64);
    if (tid == 0) {
      sfl[0] = (cnt >= 205) ? 1 : 0;
      sfl[1] = big ? 1 : 0;
      if (blockIdx.x == 0) { flags[0] = sfl[0]; flags[1] = sfl[1]; }
    }
  }
  __syncthreads();
  const int isbf = sfl[0], m8 = sfl[1];

  int id = blockIdx.x * 256 + tid;
  const int n0 = BN * CH, n1 = NB * NV * 3, n2 = P_TOT, n3 = BN;
  if (id < n0) { xcan[id] = cvt(xin, id, isbf); return; }
  id -= n0;
  if (id < n1) { ccan[id] = cvt(coords, id, isbf); return; }
  id -= n1;
  if (id < n2) {
    const void* src; int off;
    if      (id < P_LN1B)  { src = ln1g;  off = id - P_LN1G; }
    else if (id < P_LN2G)  { src = ln1b;  off = id - P_LN1B; }
    else if (id < P_LN2B)  { src = ln2g;  off = id - P_LN2G; }
    else if (id < P_WQKV)  { src = ln2b;  off = id - P_LN2B; }
    else if (id < P_BQKV)  { src = wqkv;  off = id - P_WQKV; }
    else if (id < P_WPROJ) { src = bqkv;  off = id - P_BQKV; }
    else if (id < P_BPROJ) { src = wproj; off = id - P_WPROJ; }
    else if (id < P_W1)    { src = bproj; off = id - P_BPROJ; }
    else if (id < P_B1)    { src = w1;    off = id - P_W1; }
    else if (id < P_W2)    { src = b1;    off = id - P_B1; }
    else if (id < P_B2)    { src = w2;    off = id - P_W2; }
    else                   { src = b2;    off = id - P_B2; }
    pcan[id] = cvt(src, off, isbf);
    return;
  }
  id -= n2;
  if (id < n3) {
    mcan[id] = m8 ? (int)(((const unsigned char*)maskr)[id] != 0)
                  : (int)(((const int*)maskr)[id] != 0);
    return;
  }
  id -= n3;
  // ---- pack (reads RAW weight inputs; B-frag layout for 16x16x32) ----
  if (id < 16384) {            // w1: K=64, N=256 -> nt 0..15, kh 0..1
    int j = id & 7, l = (id >> 3) & 63, kh = (id >> 9) & 1, nt = id >> 10;
    int k = kh * 32 + ((l >> 4) * 8) + j;
    int n = nt * 16 + (l & 15);
    w1p[id] = __bfloat16_as_ushort(__float2bfloat16(cvt(w1, k * MHID + n, isbf)));
    return;
  }
  id -= 16384;
  if (id < 16384) {            // w2: K=256, N=64 -> nt 0..3, kh 0..7
    int j = id & 7, l = (id >> 3) & 63, kh = (id >> 9) & 7, nt = id >> 12;
    int k = kh * 32 + ((l >> 4) * 8) + j;
    int n = nt * 16 + (l & 15);
    w2p[id] = __bfloat16_as_ushort(__float2bfloat16(cvt(w2, k * CH + n, isbf)));
    return;
  }
  id -= 16384;
  if (id < 12288) {            // wqkv: K=64, N=192 -> nt 0..11, kh 0..1
    int j = id & 7, l = (id >> 3) & 63, kh = (id >> 9) & 1, nt = id >> 10;
    int k = kh * 32 + ((l >> 4) * 8) + j;
    int n = nt * 16 + (l & 15);
    wqp[id] = __bfloat16_as_ushort(__float2bfloat16(cvt(wqkv, k * 192 + n, isbf)));
  }
}

// ---------------- K1: LN1 + QKV — MFMA version ----------------
#define XQS 72
__global__ __launch_bounds__(256) void k_ln_qkv(
    const float* __restrict__ x, const float* __restrict__ pcan,
    const unsigned short* __restrict__ wqp, float* __restrict__ qkv)
{
  __shared__ unsigned short xnb[16 * XQS];
  const int tid = threadIdx.x;
  const int wave = tid >> 6, lane = tid & 63;
  const int row0 = blockIdx.x * 16;

  {
    const float gg = pcan[P_LN1G + lane], bb = pcan[P_LN1B + lane];
#pragma unroll
    for (int r = 0; r < 4; ++r) {
      int m = wave * 4 + r;
      float v = x[(size_t)(row0 + m) * CH + lane];
      float mn = wave_sum_f32(v) * (1.0f / 64.0f);
      float d = v - mn;
      float var = wave_sum_f32(d * d) * (1.0f / 64.0f);
      float rs = 1.0f / sqrtf(var + 1e-5f);
      xnb[m * XQS + lane] =
          __bfloat16_as_ushort(__float2bfloat16(d * rs * gg + bb));
    }
  }
  __syncthreads();

  const int q = lane >> 4, c = lane & 15;
  short8 a0 = *(const short8*)&xnb[c * XQS + q * 8];
  short8 a1 = *(const short8*)&xnb[c * XQS + 32 + q * 8];

#pragma unroll
  for (int t = 0; t < 3; ++t) {
    int nt = wave * 3 + t;
    short8 b0 = *(const short8*)&wqp[(size_t)((nt * 2 + 0) * 64 + lane) * 8];
    short8 b1 = *(const short8*)&wqp[(size_t)((nt * 2 + 1) * 64 + lane) * 8];
    float4a z = {0.f, 0.f, 0.f, 0.f};
    z = __builtin_amdgcn_mfma_f32_16x16x32_bf16(a0, b0, z, 0, 0, 0);
    z = __builtin_amdgcn_mfma_f32_16x16x32_bf16(a1, b1, z, 0, 0, 0);
    int n = nt * 16 + c;
    float bq = pcan[P_BQKV + n];
#pragma unroll
    for (int r = 0; r < 4; ++r) {
      int m = q * 4 + r;
      qkv[(size_t)(row0 + m) * 192 + n] = z[r] + bq;
    }
  }
}

// ---------------- K2a: bin valid points into 16^3 unit cells ----------------
// One block per batch. Counting sort: LDS count -> scan -> scatter.
// pbin[slot] = (x, y, z, idx_bits); bstart[c] = exclusive start of cell c,
// bstart[4096] = nvalid.
__global__ __launch_bounds__(1024) void k_bin(
    const float* __restrict__ ccan, const int* __restrict__ mcan,
    float4* __restrict__ pbin, unsigned* __restrict__ bstart)
{
  __shared__ unsigned cnt[NV];
  __shared__ unsigned woff[16];
  const int b = blockIdx.x, tid = threadIdx.x;
  const float* cb = ccan + (size_t)b * NV * 3;
  const int* mb = mcan + b * NV;
  unsigned* st = bstart + (size_t)b * 4104;

#pragma unroll
  for (int k = 0; k < 4; ++k) cnt[tid + k * 1024] = 0;
  __syncthreads();

#pragma unroll
  for (int k = 0; k < 4; ++k) {
    int j = tid + k * 1024;
    if (mb[j]) {
      int cx = (int)cb[j * 3];     cx = cx > 15 ? 15 : cx;
      int cy = (int)cb[j * 3 + 1]; cy = cy > 15 ? 15 : cy;
      int cz = (int)cb[j * 3 + 2]; cz = cz > 15 ? 15 : cz;
      atomicAdd(&cnt[(cz << 8) + (cy << 4) + cx], 1u);
    }
  }
  __syncthreads();

  // exclusive scan over 4096 cells: 4 cells/thread + wave shfl scan
  unsigned s0 = cnt[tid * 4], s1 = cnt[tid * 4 + 1];
  unsigned s2 = cnt[tid * 4 + 2], s3 = cnt[tid * 4 + 3];
  unsigned tot = s0 + s1 + s2 + s3;
  unsigned v = tot;
  const int wv = tid >> 6, ln = tid & 63;
#pragma unroll
  for (int d = 1; d < 64; d <<= 1) {
    unsigned o = __shfl_up(v, d, 64);
    if (ln >= d) v += o;
  }
  if (ln == 63) woff[wv] = v;
  __syncthreads();
  unsigned wpre = 0;
  for (int w = 0; w < wv; ++w) wpre += woff[w];
  unsigned r = wpre + v - tot;   // exclusive prefix for this thread's 4 cells
  cnt[tid * 4]     = r; st[tid * 4]     = r; r += s0;
  cnt[tid * 4 + 1] = r; st[tid * 4 + 1] = r; r += s1;
  cnt[tid * 4 + 2] = r; st[tid * 4 + 2] = r; r += s2;
  cnt[tid * 4 + 3] = r; st[tid * 4 + 3] = r; r += s3;
  if (tid == 1023) st[4096] = r;   // nvalid
  __syncthreads();

  // scatter (cnt now = per-cell cursor)
#pragma unroll
  for (int k = 0; k < 4; ++k) {
    int j = tid + k * 1024;
    if (mb[j]) {
      float x = cb[j * 3], y = cb[j * 3 + 1], z = cb[j * 3 + 2];
      int cx = (int)x; cx = cx > 15 ? 15 : cx;
      int cy = (int)y; cy = cy > 15 ? 15 : cy;
      int cz = (int)z; cz = cz > 15 ? 15 : cz;
      unsigned pos = atomicAdd(&cnt[(cz << 8) + (cy << 4) + cx], 1u);
      float4 q; q.x = x; q.y = y; q.z = z; q.w = __int_as_float(j);
      pbin[(size_t)b * NV + pos] = q;
    }
  }
}

// ---------------- K2b: KNN via expanding Chebyshev rings ----------------
// One lane per VALID query, processed in bin order (adjacent lanes share
// cells -> low divergence, broadcast loads). Exact: same d2f expression,
// (d2bits,idx) keys; a point in a cell at Chebyshev ring >= R+1 has
// d2 > R^2 strictly, so stop when 10th-best d2 <= R^2.
// Invalid query rows are skipped entirely (reference zeroes their attn
// output; k_attn masks nbr reads in-bounds).
__global__ __launch_bounds__(256) void k_knn2(
    const float4* __restrict__ pbin, const unsigned* __restrict__ bstart,
    int* __restrict__ nbr)
{
  const int g = blockIdx.x * 256 + threadIdx.x;
  const int b = g >> 12, slot = g & (NV - 1);
  const unsigned* st = bstart + (size_t)b * 4104;
  const int nval = (int)st[4096];
  if (slot >= nval) return;
  const float4* pb = pbin + (size_t)b * NV;
  float4 me = pb[slot];
  const float qx = me.x, qy = me.y, qz = me.z;
  const int qi = __float_as_int(me.w);
  int cx = (int)qx; cx = cx > 15 ? 15 : cx;
  int cy = (int)qy; cy = cy > 15 ? 15 : cy;
  int cz = (int)qz; cz = cz > 15 ? 15 : cz;

  unsigned long long arr[KNN];
#pragma unroll
  for (int t = 0; t < KNN; ++t) arr[t] = ~0ull;

  for (int R = 0; R < 16; ++R) {
    const int zlo = cz - R, zhi = cz + R;
    const int z0 = zlo < 0 ? 0 : zlo, z1 = zhi > 15 ? 15 : zhi;
    for (int z = z0; z <= z1; ++z) {
      const bool zed = (z == zlo) || (z == zhi);
      const int ylo = cy - R, yhi = cy + R;
      const int y0 = ylo < 0 ? 0 : ylo, y1 = yhi > 15 ? 15 : yhi;
      for (int y = y0; y <= y1; ++y) {
        const bool yed = (y == ylo) || (y == yhi);
        const int base = (z << 8) + (y << 4);
        if (zed || yed) {
          // full x row: cells contiguous -> one candidate span
          const int xa = (cx - R) < 0 ? 0 : (cx - R);
          const int xb = (cx + R) > 15 ? 15 : (cx + R);
          const int s = (int)st[base + xa], e = (int)st[base + xb + 1];
          for (int i = s; i < e; ++i) {
            float4 p = pb[i];
            float d2 = d2f(p.x, p.y, p.z, qx, qy, qz);
            unsigned long long key =
                ((unsigned long long)__float_as_uint(d2) << 32) |
                (unsigned)__float_as_int(p.w);
            knn_insert(arr, key);
          }
        } else {
          // interior row (R>=1): only the two x-edge cells
          const int xl = cx - R, xr = cx + R;
          if (xl >= 0) {
            const int s = (int)st[base + xl], e = (int)st[base + xl + 1];
            for (int i = s; i < e; ++i) {
              float4 p = pb[i];
              float d2 = d2f(p.x, p.y, p.z, qx, qy, qz);
              unsigned long long key =
                  ((unsigned long long)__float_as_uint(d2) << 32) |
                  (unsigned)__float_as_int(p.w);
              knn_insert(arr, key);
            }
          }
          if (xr <= 15) {
            const int s = (int)st[base + xr], e = (int)st[base + xr + 1];
            for (int i = s; i < e; ++i) {
              float4 p = pb[i];
              float d2 = d2f(p.x, p.y, p.z, qx, qy, qz);
              unsigned long long key =
                  ((unsigned long long)__float_as_uint(d2) << 32) |
                  (unsigned)__float_as_int(p.w);
              knn_insert(arr, key);
            }
          }
        }
      }
    }
    if (arr[KNN - 1] != ~0ull) {
      float dk = __uint_as_float((unsigned)(arr[KNN - 1] >> 32));
      if (dk <= (float)(R * R)) break;
    }
  }

  const int row = (b << 12) | qi;
#pragma unroll
  for (int t = 0; t < KNN; ++t)
    nbr[(size_t)row * KNN + t] = (int)(arr[t] & (NV - 1));
}

// ---------------- K3: attention + proj + residual ----------------
// Dead (masked) query rows skip all attn work: reference zeroes their
// attn output, so xres = xcan exactly. Barriers stay unconditional.
#define AROWS 4
__global__ __launch_bounds__(256) void k_attn(
    const float* __restrict__ qkv, const int* __restrict__ nbr,
    const int* __restrict__ mcan, const float* __restrict__ xcan,
    const float* __restrict__ pcan, float* __restrict__ xres)
{
  __shared__ float wp[CH * CH];
  __shared__ float bp[CH];
  __shared__ float sc[AROWS][NH][KNN];
  __shared__ float wsel[AROWS][NH][KS];
  __shared__ int   isel[AROWS][NH][KS];
  __shared__ float obuf[AROWS][CH];
  __shared__ int   nb[AROWS][KNN];
  __shared__ float npen[AROWS][KNN];
  const int tid = threadIdx.x;
  {
    const float4* src = (const float4*)(pcan + P_WPROJ);
    float4* dst = (float4*)wp;
    for (int i = tid; i < CH * CH / 4; i += 256) dst[i] = src[i];
    if (tid < CH) bp[tid] = pcan[P_BPROJ + tid];
  }
  const int wave = tid >> 6, lane = tid & 63;
  const int row = blockIdx.x * AROWS + wave;
  const int b = row / NV;
  const bool live = mcan[row] != 0;

  if (live && lane < KNN) {
    int j = nbr[(size_t)row * KNN + lane] & (NV - 1);
    nb[wave][lane] = j;
    npen[wave][lane] = mcan[b * NV + j] ? 0.0f : -1e9f;
  }
  __syncthreads();

  if (live && lane < NH * KNN) {
    int h = lane / KNN, kk = lane % KNN;
    int j = nb[wave][kk];
    const float* qp = qkv + (size_t)row * 192 + h * DH;
    const float* kp = qkv + ((size_t)(b * NV + j)) * 192 + 64 + h * DH;
    float acc = 0.f;
#pragma unroll
    for (int d = 0; d < DH; ++d) acc += qp[d] * kp[d];
    sc[wave][h][kk] = acc * 0.25f + npen[wave][kk];
  }
  __syncthreads();

  if (live && lane < NH) {
    int h = lane;
    float sv[KS]; int sj[KS];
    unsigned used = 0;
#pragma unroll
    for (int r = 0; r < KS; ++r) {
      float best = -INFINITY; int bi = 0;
#pragma unroll
      for (int kk = 0; kk < KNN; ++kk) {
        float s = sc[wave][h][kk];
        if (!(used & (1u << kk)) && s > best) { best = s; bi = kk; }
      }
      used |= 1u << bi; sv[r] = best; sj[r] = bi;
    }
    float mx = sv[0];
    float e[KS], sum = 0.f;
#pragma unroll
    for (int r = 0; r < KS; ++r) { e[r] = expf(sv[r] - mx); sum += e[r]; }
    float inv = 1.0f / sum;
#pragma unroll
    for (int r = 0; r < KS; ++r) {
      wsel[wave][h][r] = e[r] * inv;
      isel[wave][h][r] = nb[wave][sj[r]];
    }
  }
  __syncthreads();

  if (live) {
    int h = lane >> 4, d = lane & 15;
    float o = 0.f;
#pragma unroll
    for (int r = 0; r < KS; ++r) {
      int j = isel[wave][h][r];
      o += wsel[wave][h][r] * qkv[((size_t)(b * NV + j)) * 192 + 128 + h * DH + d];
    }
    obuf[wave][lane] = o;
  }
  __syncthreads();

  if (live) {
    float acc = bp[lane];
#pragma unroll 4
    for (int cc = 0; cc < CH; ++cc)
      acc = fmaf(obuf[wave][cc], wp[cc * CH + lane], acc);
    xres[(size_t)row * CH + lane] = 0.5f * acc + xcan[(size_t)row * CH + lane];
  } else {
    xres[(size_t)row * CH + lane] = xcan[(size_t)row * CH + lane];
  }
}

// ---------------- K4: LN2 + MLP + residual — MFMA version ----------------
#define XNS 72
#define GS  264
__global__ __launch_bounds__(256) void k_mlp(
    const float* __restrict__ xres, const float* __restrict__ pcan,
    const unsigned short* __restrict__ w1p,
    const unsigned short* __restrict__ w2p,
    const int* __restrict__ flags, void* __restrict__ out)
{
  __shared__ unsigned short xnb[16 * XNS];
  __shared__ unsigned short gb[16 * GS];
  const int tid = threadIdx.x;
  const int wave = tid >> 6, lane = tid & 63;
  const int row0 = blockIdx.x * 16;

  {
    const float gg = pcan[P_LN2G + lane], bb2 = pcan[P_LN2B + lane];
#pragma unroll
    for (int r = 0; r < 4; ++r) {
      int m = wave * 4 + r;
      float v = xres[(size_t)(row0 + m) * CH + lane];
      float mn = wave_sum_f32(v) * (1.0f / 64.0f);
      float d = v - mn;
      float var = wave_sum_f32(d * d) * (1.0f / 64.0f);
      float rs = 1.0f / sqrtf(var + 1e-5f);
      xnb[m * XNS + lane] =
          __bfloat16_as_ushort(__float2bfloat16(d * rs * gg + bb2));
    }
  }
  __syncthreads();

  const int q = lane >> 4, c = lane & 15;
  short8 a0 = *(const short8*)&xnb[c * XNS + q * 8];
  short8 a1 = *(const short8*)&xnb[c * XNS + 32 + q * 8];

  // ---- fc1 ----
  float4a acc[4];
#pragma unroll
  for (int t = 0; t < 4; ++t) {
    int nt = wave * 4 + t;
    short8 b0 = *(const short8*)&w1p[(size_t)((nt * 2 + 0) * 64 + lane) * 8];
    short8 b1 = *(const short8*)&w1p[(size_t)((nt * 2 + 1) * 64 + lane) * 8];
    float4a z = {0.f, 0.f, 0.f, 0.f};
    z = __builtin_amdgcn_mfma_f32_16x16x32_bf16(a0, b0, z, 0, 0, 0);
    z = __builtin_amdgcn_mfma_f32_16x16x32_bf16(a1, b1, z, 0, 0, 0);
    acc[t] = z;
  }
#pragma unroll
  for (int t = 0; t < 4; ++t) {
    int n = (wave * 4 + t) * 16 + c;
    float bo = pcan[P_B1 + n];
#pragma unroll
    for (int r = 0; r < 4; ++r) {
      float h = acc[t][r] + bo;
      float u = 0.7978845608028654f * (h + 0.044715f * h * h * h);
      float gv = 0.5f * h * (1.0f + tanh_fast(u));
      gb[(q * 4 + r) * GS + n] = __bfloat16_as_ushort(__float2bfloat16(gv));
    }
  }
  __syncthreads();

  // ---- fc2 ----
  float4a o = {0.f, 0.f, 0.f, 0.f};
#pragma unroll
  for (int kh = 0; kh < 8; ++kh) {
    short8 ag = *(const short8*)&gb[c * GS + kh * 32 + q * 8];
    short8 bg = *(const short8*)&w2p[(size_t)((wave * 8 + kh) * 64 + lane) * 8];
    o = __builtin_amdgcn_mfma_f32_16x16x32_bf16(ag, bg, o, 0, 0, 0);
  }
  {
    int n = wave * 16 + c;
    float b2v = pcan[P_B2 + n];
    const int isbf = flags[0];
#pragma unroll
    for (int r = 0; r < 4; ++r) {
      int m = q * 4 + r;
      size_t idx = (size_t)(row0 + m) * CH + n;
      float val = 0.5f * (o[r] + b2v) + xres[idx];
      if (isbf) ((bf16*)out)[idx] = __float2bfloat16(val);
      else      ((float*)out)[idx] = val;
    }
  }
}

extern "C" void kernel_launch(void* const* d_in, const int* in_sizes, int n_in,
                              void* d_out, int out_size, void* d_ws, size_t ws_size,
                              hipStream_t stream)
{
  char* ws = (char*)d_ws;
  float* qkv   = (float*)(ws);
  float* xres  = (float*)(ws + 12582912);
  float* xcan  = (float*)(ws + 16777216);
  float* ccan  = (float*)(ws + 20971520);
  float* pcan  = (float*)(ws + 21168128);
  int*   mcan  = (int*)  (ws + 21368064);
  int*   nbr   = (int*)  (ws + 21433600);
  int*   flags = (int*)  (ws + 22088960);
  unsigned short* w1p = (unsigned short*)(ws + 22089728);   // 32 KB
  unsigned short* w2p = (unsigned short*)(ws + 22122496);   // 32 KB
  unsigned short* wqp = (unsigned short*)(ws + 22155264);   // 24 KB
  float4*   pbin   = (float4*)  (ws + 22179840);            // 256 KB
  unsigned* bstart = (unsigned*)(ws + 22441984);            // 64 KB

  const int total = N_ING + N_PACK;
  k_prep<<<(total + 255) / 256, 256, 0, stream>>>(
      d_in[0], d_in[1], d_in[2], d_in[3], d_in[4], d_in[5], d_in[6],
      d_in[7], d_in[8], d_in[9], d_in[10], d_in[11], d_in[12], d_in[13], d_in[14],
      xcan, ccan, pcan, mcan, w1p, w2p, wqp, flags);
  k_bin<<<NB, 1024, 0, stream>>>(ccan, mcan, pbin, bstart);
  k_ln_qkv<<<BN / 16, 256, 0, stream>>>(xcan, pcan, wqp, qkv);
  k_knn2<<<BN / 256, 256, 0, stream>>>(pbin, bstart, nbr);
  k_attn<<<BN / AROWS, 256, 0, stream>>>(qkv, nbr, mcan, xcan, pcan, xres);
  k_mlp<<<BN / 16, 256, 0, stream>>>(xres, pcan, w1p, w2p, flags, d_out);
}